// Round 10
// baseline (129.081 us; speedup 1.0000x reference)
//
#include <hip/hip_runtime.h>

#define B_ 8
#define C_ 256
#define CI_ 128
#define N_ 4096
#define M_ 1024

typedef unsigned short u16;
typedef unsigned int u32;
typedef __bf16 bf16x8 __attribute__((ext_vector_type(8)));
typedef _Float16 f16x8 __attribute__((ext_vector_type(8)));
typedef float f32x4 __attribute__((ext_vector_type(4)));
typedef u16 u16x4 __attribute__((ext_vector_type(4)));
typedef u16 u16x8 __attribute__((ext_vector_type(8)));

__device__ __forceinline__ float bf2f(u16 u) {
    u32 i = ((u32)u) << 16;
    float f;
    __builtin_memcpy(&f, &i, 4);
    return f;
}
__device__ __forceinline__ u16 f2bf(float f) {
    u32 i;
    __builtin_memcpy(&i, &f, 4);
    u32 r = (i + 0x7fffu + ((i >> 16) & 1u)) >> 16;
    return (u16)r;
}
__device__ __forceinline__ u16 f2h(float f) {
    _Float16 h = (_Float16)f;
    u16 u;
    __builtin_memcpy(&u, &h, 2);
    return u;
}
__device__ __forceinline__ float h2f(u16 u) {
    _Float16 h;
    __builtin_memcpy(&h, &u, 2);
    return (float)h;
}
__device__ __forceinline__ void split_bf(float v, u16& hi, u16& lo) {
    hi = f2bf(v);
    lo = f2bf(v - bf2f(hi));
}
__device__ __forceinline__ bf16x8 ldb8(const u16* p) {
    return *reinterpret_cast<const bf16x8*>(p);
}
__device__ __forceinline__ f16x8 ldh8(const u16* p) {
    return *reinterpret_cast<const f16x8*>(p);
}
__device__ __forceinline__ f32x4 MFMAB(bf16x8 a, bf16x8 b, f32x4 c) {
    return __builtin_amdgcn_mfma_f32_16x16x32_bf16(a, b, c, 0, 0, 0);
}
__device__ __forceinline__ f32x4 MFMAH(f16x8 a, f16x8 b, f32x4 c) {
    return __builtin_amdgcn_mfma_f32_16x16x32_f16(a, b, c, 0, 0, 0);
}

// fragment-linear layout: [tile16][ks][lane(64)][8]; value (row-in-16 = lane&15,
// k = ks*32 + (lane>>4)*8 + e). Same layout serves as A-frag (row) or B-frag (col).

// ---------------- weight prep ----------------
__global__ __launch_bounds__(256) void k_prep(
    const float* __restrict__ tw, const float* __restrict__ tb,
    const float* __restrict__ pw, const float* __restrict__ pb,
    const float* __restrict__ gw, const float* __restrict__ gb,
    const float* __restrict__ Ww,
    u16* __restrict__ wcf_h, u16* __restrict__ wcf_l,
    float* __restrict__ bcat, u16* __restrict__ wwf) {
    int idx = blockIdx.x * 256 + threadIdx.x;
    if (idx < 384 * 256) {
        int r = idx >> 8, c = idx & 255;
        float v = (r < 128) ? tw[r * 256 + c]
                : (r < 256) ? pw[(r - 128) * 256 + c]
                            : gw[(r - 256) * 256 + c];
        u16 h, l;
        split_bf(v, h, l);
        size_t off = (size_t)((r >> 4) * 8 + (c >> 5)) * 512 +
                     (((c >> 3) & 3) * 16 + (r & 15)) * 8 + (c & 7);
        wcf_h[off] = h;
        wcf_l[off] = l;
    } else if (idx < 384 * 256 + 256 * 128) {
        int k2 = idx - 384 * 256;
        int c = k2 >> 7, k = k2 & 127;
        size_t off = (size_t)((c >> 4) * 4 + (k >> 5)) * 512 +
                     (((k >> 3) & 3) * 16 + (c & 15)) * 8 + (k & 7);
        wwf[off] = f2h(Ww[k2]);
    } else if (idx < 384 * 256 + 256 * 128 + 384) {
        int r = idx - (384 * 256 + 256 * 128);
        bcat[r] = (r < 128) ? tb[r] : (r < 256) ? pb[r - 128] : gb[r - 256];
    }
}

// ---------------- x (B,C,N) fp32 -> fragment-linear split bf16 ----------------
__global__ __launch_bounds__(256) void k_tx(const float* __restrict__ x,
                                            u16* __restrict__ xbf_h, u16* __restrict__ xbf_l) {
    int bid = blockIdx.x;
    int b = bid >> 8, rem = bid & 255, nt = rem >> 2, ct = rem & 3;
    int n0 = nt * 64, c0 = ct * 64;
    __shared__ u16 th_[64][66];
    __shared__ u16 tl_[64][66];
    int j = threadIdx.x & 63, i0 = threadIdx.x >> 6;
    for (int i = i0; i < 64; i += 4) {
        float v = x[((size_t)b * C_ + c0 + i) * N_ + n0 + j];
        u16 h, l;
        split_bf(v, h, l);
        th_[i][j] = h;
        tl_[i][j] = l;
    }
    __syncthreads();
    int w = threadIdx.x >> 6, lane = threadIdx.x & 63;
    int l15 = lane & 15, g16 = lane >> 4;
    int s = w;
#pragma unroll
    for (int kk = 0; kk < 2; ++kk) {
        u16x8 hv, lv;
#pragma unroll
        for (int e = 0; e < 8; ++e) {
            hv[e] = th_[kk * 32 + g16 * 8 + e][s * 16 + l15];
            lv[e] = tl_[kk * 32 + g16 * 8 + e][s * 16 + l15];
        }
        size_t off = ((size_t)(b * 256 + (n0 >> 4) + s) * 8 + (c0 >> 5) + kk) * 512 +
                     (size_t)lane * 8;
        *(u16x8*)&xbf_h[off] = hv;
        *(u16x8*)&xbf_l[off] = lv;
    }
}

// ---------------- projection GEMM + fused 2x2 pooling epilogue ----------------
__global__ __launch_bounds__(256) void k_proj(
    const u16* __restrict__ wcf_h, const u16* __restrict__ wcf_l,
    const float* __restrict__ bcat,
    const u16* __restrict__ xbf_h, const u16* __restrict__ xbf_l,
    u16* __restrict__ thf, u16* __restrict__ ppf, u16* __restrict__ gpf) {
    int bid = blockIdx.x;
    int b = bid / 96, rem = bid % 96, rt = rem >> 5, nt = rem & 31;
    int tid = threadIdx.x;
    int w = tid >> 6, lane = tid & 63;
    int l15 = lane & 15, g16 = lane >> 4;
    int wr = (w >> 1) * 64, wc = (w & 1) * 64;
    int rbase = rt * 128 + wr, nbase = nt * 128 + wc;
    __shared__ u16 tl[128][132];
    f32x4 acc[4][4];
#pragma unroll
    for (int i = 0; i < 4; ++i)
#pragma unroll
        for (int j = 0; j < 4; ++j)
#pragma unroll
            for (int r = 0; r < 4; ++r) acc[i][j][r] = 0.f;
#pragma unroll
    for (int ks = 0; ks < 8; ++ks) {
        bf16x8 ah[4], al[4], bh[4], bl[4];
#pragma unroll
        for (int i = 0; i < 4; ++i) {
            size_t o = ((size_t)((rbase >> 4) + i) * 8 + ks) * 512 + (size_t)lane * 8;
            ah[i] = ldb8(&wcf_h[o]);
            al[i] = ldb8(&wcf_l[o]);
        }
#pragma unroll
        for (int j = 0; j < 4; ++j) {
            size_t o = ((size_t)(b * 256 + (nbase >> 4) + j) * 8 + ks) * 512 + (size_t)lane * 8;
            bh[j] = ldb8(&xbf_h[o]);
            bl[j] = ldb8(&xbf_l[o]);
        }
#pragma unroll
        for (int i = 0; i < 4; ++i)
#pragma unroll
            for (int j = 0; j < 4; ++j) {
                acc[i][j] = MFMAB(ah[i], bh[j], acc[i][j]);
                acc[i][j] = MFMAB(ah[i], bl[j], acc[i][j]);
                acc[i][j] = MFMAB(al[i], bh[j], acc[i][j]);
            }
    }
    if (rt == 0) {
#pragma unroll
        for (int i = 0; i < 4; ++i) {
            int lrow = wr + i * 16 + g16 * 4;
#pragma unroll
            for (int j = 0; j < 4; ++j) {
                u16x4 pk;
#pragma unroll
                for (int r = 0; r < 4; ++r)
                    pk[r] = f2h(acc[i][j][r] + bcat[lrow + r]);
                size_t off = ((size_t)(b * 256 + (nbase >> 4) + j) * 4 + (lrow >> 5)) * 512 +
                             (((lrow >> 3) & 3) * 16 + l15) * 8 + (lrow & 7);
                *reinterpret_cast<u16x4*>(&thf[off]) = pk;
            }
        }
    } else {
#pragma unroll
        for (int i = 0; i < 4; ++i) {
            int lrow = wr + i * 16 + g16 * 4;
#pragma unroll
            for (int j = 0; j < 4; ++j) {
                int n_loc = wc + j * 16 + l15;
                u16x4 pk;
#pragma unroll
                for (int r = 0; r < 4; ++r)
                    pk[r] = f2h(acc[i][j][r] + bcat[rt * 128 + lrow + r]);
                *reinterpret_cast<u16x4*>(&tl[n_loc][lrow]) = pk;
            }
        }
        __syncthreads();
        if (rt == 1) {
#pragma unroll
            for (int half = 0; half < 2; ++half) {
                int w2 = (tid >> 4) + half * 16;
                int c8 = tid & 15;
                u16x8 v0 = *(const u16x8*)&tl[2 * w2][c8 * 8];
                u16x8 v1 = *(const u16x8*)&tl[2 * w2 + 1][c8 * 8];
                u16x8 v2 = *(const u16x8*)&tl[64 + 2 * w2][c8 * 8];
                u16x8 v3 = *(const u16x8*)&tl[65 + 2 * w2][c8 * 8];
                u16x8 o;
#pragma unroll
                for (int e = 0; e < 8; ++e) {
                    float mx = fmaxf(fmaxf(h2f(v0[e]), h2f(v1[e])),
                                     fmaxf(h2f(v2[e]), h2f(v3[e])));
                    o[e] = f2h(mx);
                }
                size_t off = ((size_t)(((b * 32 + nt) * 2 + (w2 >> 4)) * 4 + (c8 >> 2)) * 64 +
                              (c8 & 3) * 16 + (w2 & 15)) * 8;
                *(u16x8*)&ppf[off] = o;
            }
        } else {
#pragma unroll
            for (int s = 0; s < 2; ++s) {
                int wg = (tid >> 7) + s * 2;
                int ci = tid & 127;
                u16x8 o;
#pragma unroll
                for (int e = 0; e < 8; ++e) {
                    int w2 = wg * 8 + e;
                    float v = fmaxf(fmaxf(h2f(tl[2 * w2][ci]), h2f(tl[2 * w2 + 1][ci])),
                                    fmaxf(h2f(tl[64 + 2 * w2][ci]), h2f(tl[65 + 2 * w2][ci])));
                    o[e] = f2h(v);
                }
                size_t off = ((size_t)((b * 32 + nt) * 8 + (ci >> 4)) * 64 + wg * 16 +
                              (ci & 15)) * 8;
                *(u16x8*)&gpf[off] = o;
            }
        }
    }
}

// ---------------- flash attention (q_tile=128: 32 q/warp, split-m=4) ----------
// 1024 blocks; each block sweeps M/4=256 m for 128 q-columns. Per iter, the
// 16KB K/V LDS tile feeds 32 MFMAs/warp (2x the old arithmetic intensity).
__global__ __launch_bounds__(256) void k_attn(
    const u16* __restrict__ thf, const u16* __restrict__ ppf,
    const u16* __restrict__ gpf,
    u16* __restrict__ of, float2* __restrict__ ml) {
    int bid = blockIdx.x;
    int b = bid & 7, r = bid >> 3;   // same-b blocks -> same XCD (L2 locality)
    int sp = r >> 5, nt = r & 31;    // sp in 0..3, nt in 0..31
    int tid = threadIdx.x;
    int w = tid >> 6, lane = tid & 63;
    int l15 = lane & 15, g16 = lane >> 4;
    __shared__ u16 kv[8192];            // [0,4096): K-tile, [4096,8192): V-tile
    __shared__ u16 plds[4][2][16][40];  // per-warp, per-q-group P transpose

    // two q-groups per warp: global n-16-tile = nt*8 + w*2 + qg
    f16x8 qf[2][4];
#pragma unroll
    for (int qg = 0; qg < 2; ++qg)
#pragma unroll
        for (int ks = 0; ks < 4; ++ks)
            qf[qg][ks] = ldh8(&thf[((size_t)(b * 256 + nt * 8 + w * 2 + qg) * 4 + ks) * 512 +
                                   (size_t)lane * 8]);

    f32x4 o[2][8];
#pragma unroll
    for (int qg = 0; qg < 2; ++qg)
#pragma unroll
        for (int ct = 0; ct < 8; ++ct)
#pragma unroll
            for (int rr = 0; rr < 4; ++rr) o[qg][ct][rr] = 0.f;
    float mrun[2] = {-1e30f, -1e30f}, lpart[2] = {0.f, 0.f};

    int itg0 = sp * 8;
    for (int it = 0; it < 8; ++it) {
        const u16* ps = &ppf[(size_t)(b * 32 + itg0 + it) * 4096];
        const u16* gs = &gpf[(size_t)(b * 32 + itg0 + it) * 4096];
        if (it) __syncthreads();  // prior iter's kv reads complete
        *(u16x8*)&kv[tid * 8]        = *(const u16x8*)&ps[tid * 8];
        *(u16x8*)&kv[2048 + tid * 8] = *(const u16x8*)&ps[2048 + tid * 8];
        *(u16x8*)&kv[4096 + tid * 8] = *(const u16x8*)&gs[tid * 8];
        *(u16x8*)&kv[6144 + tid * 8] = *(const u16x8*)&gs[2048 + tid * 8];
        __syncthreads();  // staged tile visible

        f32x4 s[2][2];
#pragma unroll
        for (int qg = 0; qg < 2; ++qg)
#pragma unroll
            for (int h = 0; h < 2; ++h)
#pragma unroll
                for (int rr = 0; rr < 4; ++rr) s[qg][h][rr] = 0.f;
#pragma unroll
        for (int ks = 0; ks < 4; ++ks) {
            f16x8 pa0 = ldh8(&kv[ks * 512 + lane * 8]);
            f16x8 pa1 = ldh8(&kv[2048 + ks * 512 + lane * 8]);
#pragma unroll
            for (int qg = 0; qg < 2; ++qg) {
                s[qg][0] = MFMAH(pa0, qf[qg][ks], s[qg][0]);
                s[qg][1] = MFMAH(pa1, qf[qg][ks], s[qg][1]);
            }
        }
#pragma unroll
        for (int qg = 0; qg < 2; ++qg) {
            float pm8 = s[qg][0][0];
#pragma unroll
            for (int rr = 1; rr < 4; ++rr) pm8 = fmaxf(pm8, s[qg][0][rr]);
#pragma unroll
            for (int rr = 0; rr < 4; ++rr) pm8 = fmaxf(pm8, s[qg][1][rr]);
            if (__any(pm8 > mrun[qg] + 8.0f)) {
                float pm = fmaxf(pm8, __shfl_xor(pm8, 16));
                pm = fmaxf(pm, __shfl_xor(pm, 32));
                float mnew = fmaxf(mrun[qg], pm);
                float sc = __expf(mrun[qg] - mnew);
#pragma unroll
                for (int ct = 0; ct < 8; ++ct)
#pragma unroll
                    for (int rr = 0; rr < 4; ++rr) o[qg][ct][rr] *= sc;
                lpart[qg] *= sc;
                mrun[qg] = mnew;
            }
            u16x4 pk0, pk1;
#pragma unroll
            for (int rr = 0; rr < 4; ++rr) {
                float p0 = __expf(s[qg][0][rr] - mrun[qg]);
                float p1 = __expf(s[qg][1][rr] - mrun[qg]);
                lpart[qg] += p0 + p1;
                pk0[rr] = f2h(p0);
                pk1[rr] = f2h(p1);
            }
            *reinterpret_cast<u16x4*>(&plds[w][qg][l15][g16 * 4]) = pk0;
            *reinterpret_cast<u16x4*>(&plds[w][qg][l15][16 + g16 * 4]) = pk1;
        }
        __syncthreads();  // plds visible
        f16x8 pfr0 = ldh8(&plds[w][0][l15][g16 * 8]);
        f16x8 pfr1 = ldh8(&plds[w][1][l15][g16 * 8]);
#pragma unroll
        for (int ct = 0; ct < 8; ++ct) {
            f16x8 gfr = ldh8(&kv[4096 + ct * 512 + lane * 8]);
            o[0][ct] = MFMAH(gfr, pfr0, o[0][ct]);
            o[1][ct] = MFMAH(gfr, pfr1, o[1][ct]);
        }
    }
#pragma unroll
    for (int qg = 0; qg < 2; ++qg) {
        float lcol = lpart[qg] + __shfl_xor(lpart[qg], 16);
        lcol += __shfl_xor(lcol, 32);
        float linv = 1.f / lcol;
        int n = nt * 128 + w * 32 + qg * 16 + l15;
        size_t obase = ((size_t)(b * 4 + sp) * N_ + n) * CI_;
#pragma unroll
        for (int ct = 0; ct < 8; ++ct) {
            u16x4 pk;
#pragma unroll
            for (int rr = 0; rr < 4; ++rr) pk[rr] = f2h(o[qg][ct][rr] * linv);
            *reinterpret_cast<u16x4*>(&of[obase + ct * 16 + g16 * 4]) = pk;
        }
        if (g16 == 0) ml[(size_t)(b * 4 + sp) * N_ + n] = make_float2(mrun[qg], lcol);
    }
}

// ---------------- W conv GEMM (fused 4-split combine + fp16 GEMM) ----------------
__global__ __launch_bounds__(256) void k_wconv(
    const u16* __restrict__ wwf, const float* __restrict__ Wb,
    const u16* __restrict__ of, const float2* __restrict__ ml,
    u16* __restrict__ z) {
    int bid = blockIdx.x;
    int b = bid >> 6, rem = bid & 63, ct2 = rem >> 5, nt = rem & 31;
    int w = threadIdx.x >> 6, lane = threadIdx.x & 63;
    int l15 = lane & 15, g16 = lane >> 4;
    int nbase = nt * 128 + (w >> 1) * 64;
    int cbase = ct2 * 128 + (w & 1) * 64;
    const size_t spstride = (size_t)N_ * CI_;
    float wsp[4][4];
#pragma unroll
    for (int i = 0; i < 4; ++i) {
        int n = nbase + i * 16 + l15;
        float2 m0 = ml[(size_t)(b * 4 + 0) * N_ + n];
        float2 m1 = ml[(size_t)(b * 4 + 1) * N_ + n];
        float2 m2 = ml[(size_t)(b * 4 + 2) * N_ + n];
        float2 m3 = ml[(size_t)(b * 4 + 3) * N_ + n];
        float M = fmaxf(fmaxf(m0.x, m1.x), fmaxf(m2.x, m3.x));
        float w0 = __expf(m0.x - M) * m0.y;
        float w1 = __expf(m1.x - M) * m1.y;
        float w2 = __expf(m2.x - M) * m2.y;
        float w3 = __expf(m3.x - M) * m3.y;
        float invL = 1.f / (w0 + w1 + w2 + w3);
        wsp[i][0] = w0 * invL;
        wsp[i][1] = w1 * invL;
        wsp[i][2] = w2 * invL;
        wsp[i][3] = w3 * invL;
    }
    f32x4 acc[4][4];
#pragma unroll
    for (int i = 0; i < 4; ++i)
#pragma unroll
        for (int j = 0; j < 4; ++j)
#pragma unroll
            for (int r = 0; r < 4; ++r) acc[i][j][r] = 0.f;
#pragma unroll
    for (int ks = 0; ks < 4; ++ks) {
        f16x8 a[4], bb[4];
#pragma unroll
        for (int i = 0; i < 4; ++i) {
            int n = nbase + i * 16 + l15;
            size_t base = ((size_t)(b * 4) * N_ + n) * CI_ + ks * 32 + g16 * 8;
            u16x8 v0 = *(const u16x8*)&of[base];
            u16x8 v1 = *(const u16x8*)&of[base + spstride];
            u16x8 v2 = *(const u16x8*)&of[base + 2 * spstride];
            u16x8 v3 = *(const u16x8*)&of[base + 3 * spstride];
            f16x8 av;
#pragma unroll
            for (int e = 0; e < 8; ++e) {
                float vv = h2f(v0[e]) * wsp[i][0] + h2f(v1[e]) * wsp[i][1] +
                           h2f(v2[e]) * wsp[i][2] + h2f(v3[e]) * wsp[i][3];
                av[e] = (_Float16)vv;
            }
            a[i] = av;
        }
#pragma unroll
        for (int j = 0; j < 4; ++j)
            bb[j] = ldh8(&wwf[((size_t)((cbase >> 4) + j) * 4 + ks) * 512 + (size_t)lane * 8]);
#pragma unroll
        for (int i = 0; i < 4; ++i)
#pragma unroll
            for (int j = 0; j < 4; ++j) acc[i][j] = MFMAH(a[i], bb[j], acc[i][j]);
    }
#pragma unroll
    for (int j = 0; j < 4; ++j) {
        int ch = cbase + j * 16 + l15;
        float bias = Wb[ch];
        size_t rowbase = ((size_t)b * C_ + ch) * N_;
#pragma unroll
        for (int i = 0; i < 4; ++i) {
            u16x4 pk;
#pragma unroll
            for (int r = 0; r < 4; ++r) pk[r] = f2h(acc[i][j][r] + bias);
            *reinterpret_cast<u16x4*>(&z[rowbase + nbase + i * 16 + g16 * 4]) = pk;
        }
    }
}

// ---------------- BN stats + finalize ----------------
__global__ __launch_bounds__(256) void k_stats(
    const u16* __restrict__ z, const float* __restrict__ gamma,
    const float* __restrict__ beta, float* __restrict__ bnp) {
    int c = blockIdx.x;
    int tid = threadIdx.x;
    float s = 0.f, q = 0.f;
#pragma unroll
    for (int b = 0; b < B_; ++b) {
        size_t base = ((size_t)b * C_ + c) * N_ + tid * 16;
        u16x8 v0 = *(const u16x8*)&z[base];
        u16x8 v1 = *(const u16x8*)&z[base + 8];
#pragma unroll
        for (int e = 0; e < 8; ++e) {
            float v = h2f(v0[e]);
            s += v;
            q += v * v;
            float u = h2f(v1[e]);
            s += u;
            q += u * u;
        }
    }
#pragma unroll
    for (int off = 1; off <= 32; off <<= 1) {
        s += __shfl_xor(s, off);
        q += __shfl_xor(q, off);
    }
    __shared__ float ss[4], qq[4];
    int w = tid >> 6;
    if ((tid & 63) == 0) {
        ss[w] = s;
        qq[w] = q;
    }
    __syncthreads();
    if (tid == 0) {
        s = ss[0] + ss[1] + ss[2] + ss[3];
        q = qq[0] + qq[1] + qq[2] + qq[3];
        const float inv_n = 1.f / 32768.f;
        float mean = s * inv_n;
        float var = q * inv_n - mean * mean;
        float sc = gamma[c] * rsqrtf(var + 1e-5f);
        bnp[c] = sc;
        bnp[256 + c] = beta[c] - mean * sc;
    }
}

// ---------------- apply BN + residual ----------------
__global__ __launch_bounds__(256) void k_final(
    const float* __restrict__ x, const u16* __restrict__ z,
    const float* __restrict__ bnp, float* __restrict__ out) {
    int i4 = blockIdx.x * 256 + threadIdx.x;
    size_t flat = (size_t)i4 * 4;
    int c = (int)((flat >> 12) & 255);
    float sc = bnp[c], sh = bnp[256 + c];
    float4 xx = *(const float4*)&x[flat];
    u16x4 zz = *(const u16x4*)&z[flat];
    float4 oo;
    oo.x = xx.x + h2f(zz[0]) * sc + sh;
    oo.y = xx.y + h2f(zz[1]) * sc + sh;
    oo.z = xx.z + h2f(zz[2]) * sc + sh;
    oo.w = xx.w + h2f(zz[3]) * sc + sh;
    *(float4*)&out[flat] = oo;
}

extern "C" void kernel_launch(void* const* d_in, const int* in_sizes, int n_in,
                              void* d_out, int out_size, void* d_ws, size_t ws_size,
                              hipStream_t stream) {
    const float* x     = (const float*)d_in[0];
    const float* tw    = (const float*)d_in[1];
    const float* tb    = (const float*)d_in[2];
    const float* pw    = (const float*)d_in[3];
    const float* pb    = (const float*)d_in[4];
    const float* gw    = (const float*)d_in[5];
    const float* gb    = (const float*)d_in[6];
    const float* Ww    = (const float*)d_in[7];
    const float* Wb    = (const float*)d_in[8];
    const float* gamma = (const float*)d_in[9];
    const float* beta  = (const float*)d_in[10];
    float* out = (float*)d_out;

    char* p = (char*)d_ws;
    auto alloc = [&](size_t bytes) {
        char* r = p;
        p += (bytes + 255) & ~(size_t)255;
        return r;
    };
    u16* xbf_h = (u16*)alloc((size_t)B_ * N_ * C_ * 2);      // 16.8 MB, dead after k_proj
    u16* xbf_l = (u16*)alloc((size_t)B_ * N_ * C_ * 2);      // 16.8 MB, contiguous after xbf_h
    u16* thf   = (u16*)alloc((size_t)B_ * N_ * CI_ * 2);     // 8.4 MB, dead after k_attn
    u16* ppf   = (u16*)alloc((size_t)B_ * M_ * CI_ * 2);     // 2.1 MB
    u16* gpf   = (u16*)alloc((size_t)B_ * M_ * CI_ * 2);     // 2.1 MB
    float2* ml = (float2*)alloc((size_t)4 * B_ * N_ * 8);    // 1 MB
    u16* z     = (u16*)alloc((size_t)B_ * C_ * N_ * 2);      // 16.8 MB (live with of)
    u16* wcf_h = (u16*)alloc(384 * 256 * 2);
    u16* wcf_l = (u16*)alloc(384 * 256 * 2);
    u16* wwf   = (u16*)alloc(256 * 128 * 2);
    float* bcat = (float*)alloc(384 * 4);
    float* bnp  = (float*)alloc(512 * 4);
    // of (4 x 8.4 MiB fp16 partials = 33.5 MiB) aliases xbf_h+xbf_l (contiguous,
    // dead before k_attn writes).
    u16* of = xbf_h;

    k_prep<<<514, 256, 0, stream>>>(tw, tb, pw, pb, gw, gb, Ww, wcf_h, wcf_l, bcat, wwf);
    k_tx<<<2048, 256, 0, stream>>>(x, xbf_h, xbf_l);
    k_proj<<<768, 256, 0, stream>>>(wcf_h, wcf_l, bcat, xbf_h, xbf_l, thf, ppf, gpf);
    k_attn<<<1024, 256, 0, stream>>>(thf, ppf, gpf, of, ml);
    k_wconv<<<512, 256, 0, stream>>>(wwf, Wb, of, ml, z);
    k_stats<<<256, 256, 0, stream>>>(z, gamma, beta, bnp);
    k_final<<<8192, 256, 0, stream>>>(x, z, bnp, out);
}

// Round 13
// 127.008 us; speedup vs baseline: 1.0163x; 1.0163x over previous
//
#include <hip/hip_runtime.h>

#define B_ 8
#define C_ 256
#define CI_ 128
#define N_ 4096
#define M_ 1024

typedef unsigned short u16;
typedef unsigned int u32;
typedef __bf16 bf16x8 __attribute__((ext_vector_type(8)));
typedef _Float16 f16x8 __attribute__((ext_vector_type(8)));
typedef float f32x4 __attribute__((ext_vector_type(4)));
typedef u16 u16x4 __attribute__((ext_vector_type(4)));
typedef u16 u16x8 __attribute__((ext_vector_type(8)));

__device__ __forceinline__ float bf2f(u16 u) {
    u32 i = ((u32)u) << 16;
    float f;
    __builtin_memcpy(&f, &i, 4);
    return f;
}
__device__ __forceinline__ u16 f2bf(float f) {
    u32 i;
    __builtin_memcpy(&i, &f, 4);
    u32 r = (i + 0x7fffu + ((i >> 16) & 1u)) >> 16;
    return (u16)r;
}
__device__ __forceinline__ u16 f2h(float f) {
    _Float16 h = (_Float16)f;
    u16 u;
    __builtin_memcpy(&u, &h, 2);
    return u;
}
__device__ __forceinline__ float h2f(u16 u) {
    _Float16 h;
    __builtin_memcpy(&h, &u, 2);
    return (float)h;
}
__device__ __forceinline__ void split_bf(float v, u16& hi, u16& lo) {
    hi = f2bf(v);
    lo = f2bf(v - bf2f(hi));
}
__device__ __forceinline__ bf16x8 ldb8(const u16* p) {
    return *reinterpret_cast<const bf16x8*>(p);
}
__device__ __forceinline__ f16x8 ldh8(const u16* p) {
    return *reinterpret_cast<const f16x8*>(p);
}
__device__ __forceinline__ f32x4 MFMAB(bf16x8 a, bf16x8 b, f32x4 c) {
    return __builtin_amdgcn_mfma_f32_16x16x32_bf16(a, b, c, 0, 0, 0);
}
__device__ __forceinline__ f32x4 MFMAH(f16x8 a, f16x8 b, f32x4 c) {
    return __builtin_amdgcn_mfma_f32_16x16x32_f16(a, b, c, 0, 0, 0);
}

// fragment-linear layout: [tile16][ks][lane(64)][8]; value (row-in-16 = lane&15,
// k = ks*32 + (lane>>4)*8 + e). Same layout serves as A-frag (row) or B-frag (col).

// ---------------- weight prep ----------------
__global__ __launch_bounds__(256) void k_prep(
    const float* __restrict__ tw, const float* __restrict__ tb,
    const float* __restrict__ pw, const float* __restrict__ pb,
    const float* __restrict__ gw, const float* __restrict__ gb,
    const float* __restrict__ Ww,
    u16* __restrict__ wcf_h, u16* __restrict__ wcf_l,
    float* __restrict__ bcat, u16* __restrict__ wwf) {
    int idx = blockIdx.x * 256 + threadIdx.x;
    if (idx < 384 * 256) {
        int r = idx >> 8, c = idx & 255;
        float v = (r < 128) ? tw[r * 256 + c]
                : (r < 256) ? pw[(r - 128) * 256 + c]
                            : gw[(r - 256) * 256 + c];
        u16 h, l;
        split_bf(v, h, l);
        size_t off = (size_t)((r >> 4) * 8 + (c >> 5)) * 512 +
                     (((c >> 3) & 3) * 16 + (r & 15)) * 8 + (c & 7);
        wcf_h[off] = h;
        wcf_l[off] = l;
    } else if (idx < 384 * 256 + 256 * 128) {
        int k2 = idx - 384 * 256;
        int c = k2 >> 7, k = k2 & 127;
        size_t off = (size_t)((c >> 4) * 4 + (k >> 5)) * 512 +
                     (((k >> 3) & 3) * 16 + (c & 15)) * 8 + (k & 7);
        wwf[off] = f2h(Ww[k2]);
    } else if (idx < 384 * 256 + 256 * 128 + 384) {
        int r = idx - (384 * 256 + 256 * 128);
        bcat[r] = (r < 128) ? tb[r] : (r < 256) ? pb[r - 128] : gb[r - 256];
    }
}

// ---------------- x (B,C,N) fp32 -> fragment-linear split bf16 ----------------
__global__ __launch_bounds__(256) void k_tx(const float* __restrict__ x,
                                            u16* __restrict__ xbf_h, u16* __restrict__ xbf_l) {
    int bid = blockIdx.x;
    int b = bid >> 8, rem = bid & 255, nt = rem >> 2, ct = rem & 3;
    int n0 = nt * 64, c0 = ct * 64;
    __shared__ u16 th_[64][66];
    __shared__ u16 tl_[64][66];
    int j = threadIdx.x & 63, i0 = threadIdx.x >> 6;
    for (int i = i0; i < 64; i += 4) {
        float v = x[((size_t)b * C_ + c0 + i) * N_ + n0 + j];
        u16 h, l;
        split_bf(v, h, l);
        th_[i][j] = h;
        tl_[i][j] = l;
    }
    __syncthreads();
    int w = threadIdx.x >> 6, lane = threadIdx.x & 63;
    int l15 = lane & 15, g16 = lane >> 4;
    int s = w;
#pragma unroll
    for (int kk = 0; kk < 2; ++kk) {
        u16x8 hv, lv;
#pragma unroll
        for (int e = 0; e < 8; ++e) {
            hv[e] = th_[kk * 32 + g16 * 8 + e][s * 16 + l15];
            lv[e] = tl_[kk * 32 + g16 * 8 + e][s * 16 + l15];
        }
        size_t off = ((size_t)(b * 256 + (n0 >> 4) + s) * 8 + (c0 >> 5) + kk) * 512 +
                     (size_t)lane * 8;
        *(u16x8*)&xbf_h[off] = hv;
        *(u16x8*)&xbf_l[off] = lv;
    }
}

// ---------------- projection GEMM + fused 2x2 pooling epilogue ----------------
__global__ __launch_bounds__(256) void k_proj(
    const u16* __restrict__ wcf_h, const u16* __restrict__ wcf_l,
    const float* __restrict__ bcat,
    const u16* __restrict__ xbf_h, const u16* __restrict__ xbf_l,
    u16* __restrict__ thf, u16* __restrict__ ppf, u16* __restrict__ gpf) {
    int bid = blockIdx.x;
    int b = bid / 96, rem = bid % 96, rt = rem >> 5, nt = rem & 31;
    int tid = threadIdx.x;
    int w = tid >> 6, lane = tid & 63;
    int l15 = lane & 15, g16 = lane >> 4;
    int wr = (w >> 1) * 64, wc = (w & 1) * 64;
    int rbase = rt * 128 + wr, nbase = nt * 128 + wc;
    __shared__ u16 tl[128][132];
    f32x4 acc[4][4];
#pragma unroll
    for (int i = 0; i < 4; ++i)
#pragma unroll
        for (int j = 0; j < 4; ++j)
#pragma unroll
            for (int r = 0; r < 4; ++r) acc[i][j][r] = 0.f;
#pragma unroll
    for (int ks = 0; ks < 8; ++ks) {
        bf16x8 ah[4], al[4], bh[4], bl[4];
#pragma unroll
        for (int i = 0; i < 4; ++i) {
            size_t o = ((size_t)((rbase >> 4) + i) * 8 + ks) * 512 + (size_t)lane * 8;
            ah[i] = ldb8(&wcf_h[o]);
            al[i] = ldb8(&wcf_l[o]);
        }
#pragma unroll
        for (int j = 0; j < 4; ++j) {
            size_t o = ((size_t)(b * 256 + (nbase >> 4) + j) * 8 + ks) * 512 + (size_t)lane * 8;
            bh[j] = ldb8(&xbf_h[o]);
            bl[j] = ldb8(&xbf_l[o]);
        }
#pragma unroll
        for (int i = 0; i < 4; ++i)
#pragma unroll
            for (int j = 0; j < 4; ++j) {
                acc[i][j] = MFMAB(ah[i], bh[j], acc[i][j]);
                acc[i][j] = MFMAB(ah[i], bl[j], acc[i][j]);
                acc[i][j] = MFMAB(al[i], bh[j], acc[i][j]);
            }
    }
    if (rt == 0) {
#pragma unroll
        for (int i = 0; i < 4; ++i) {
            int lrow = wr + i * 16 + g16 * 4;
#pragma unroll
            for (int j = 0; j < 4; ++j) {
                u16x4 pk;
#pragma unroll
                for (int r = 0; r < 4; ++r)
                    pk[r] = f2h(acc[i][j][r] + bcat[lrow + r]);
                size_t off = ((size_t)(b * 256 + (nbase >> 4) + j) * 4 + (lrow >> 5)) * 512 +
                             (((lrow >> 3) & 3) * 16 + l15) * 8 + (lrow & 7);
                *reinterpret_cast<u16x4*>(&thf[off]) = pk;
            }
        }
    } else {
#pragma unroll
        for (int i = 0; i < 4; ++i) {
            int lrow = wr + i * 16 + g16 * 4;
#pragma unroll
            for (int j = 0; j < 4; ++j) {
                int n_loc = wc + j * 16 + l15;
                u16x4 pk;
#pragma unroll
                for (int r = 0; r < 4; ++r)
                    pk[r] = f2h(acc[i][j][r] + bcat[rt * 128 + lrow + r]);
                *reinterpret_cast<u16x4*>(&tl[n_loc][lrow]) = pk;
            }
        }
        __syncthreads();
        if (rt == 1) {
#pragma unroll
            for (int half = 0; half < 2; ++half) {
                int w2 = (tid >> 4) + half * 16;
                int c8 = tid & 15;
                u16x8 v0 = *(const u16x8*)&tl[2 * w2][c8 * 8];
                u16x8 v1 = *(const u16x8*)&tl[2 * w2 + 1][c8 * 8];
                u16x8 v2 = *(const u16x8*)&tl[64 + 2 * w2][c8 * 8];
                u16x8 v3 = *(const u16x8*)&tl[65 + 2 * w2][c8 * 8];
                u16x8 o;
#pragma unroll
                for (int e = 0; e < 8; ++e) {
                    float mx = fmaxf(fmaxf(h2f(v0[e]), h2f(v1[e])),
                                     fmaxf(h2f(v2[e]), h2f(v3[e])));
                    o[e] = f2h(mx);
                }
                size_t off = ((size_t)(((b * 32 + nt) * 2 + (w2 >> 4)) * 4 + (c8 >> 2)) * 64 +
                              (c8 & 3) * 16 + (w2 & 15)) * 8;
                *(u16x8*)&ppf[off] = o;
            }
        } else {
#pragma unroll
            for (int s = 0; s < 2; ++s) {
                int wg = (tid >> 7) + s * 2;
                int ci = tid & 127;
                u16x8 o;
#pragma unroll
                for (int e = 0; e < 8; ++e) {
                    int w2 = wg * 8 + e;
                    float v = fmaxf(fmaxf(h2f(tl[2 * w2][ci]), h2f(tl[2 * w2 + 1][ci])),
                                    fmaxf(h2f(tl[64 + 2 * w2][ci]), h2f(tl[65 + 2 * w2][ci])));
                    o[e] = f2h(v);
                }
                size_t off = ((size_t)((b * 32 + nt) * 8 + (ci >> 4)) * 64 + wg * 16 +
                              (ci & 15)) * 8;
                *(u16x8*)&gpf[off] = o;
            }
        }
    }
}

// ---------------- flash attention (split-m=4, double-buffered KV in LDS) -------
__global__ __launch_bounds__(256) void k_attn(
    const u16* __restrict__ thf, const u16* __restrict__ ppf,
    const u16* __restrict__ gpf,
    u16* __restrict__ of, float2* __restrict__ ml) {
    int bid = blockIdx.x;
    int b = bid & 7, r = bid >> 3;   // same-b blocks -> same XCD (L2 locality)
    int sp = r >> 6, nt = r & 63;    // sp in 0..3
    int tid = threadIdx.x;
    int w = tid >> 6, lane = tid & 63;
    int l15 = lane & 15, g16 = lane >> 4;
    int n = nt * 64 + w * 16 + l15;
    int t16 = nt * 4 + w;
    __shared__ u16 kv[2][8192];       // [buf][0..4096): K-tile, [4096..8192): V-tile
    __shared__ u16 plds[4][16][40];   // per-warp P transpose, padded

    f16x8 qf[4];
#pragma unroll
    for (int ks = 0; ks < 4; ++ks)
        qf[ks] = ldh8(&thf[((size_t)(b * 256 + t16) * 4 + ks) * 512 + (size_t)lane * 8]);

    f32x4 o[8];
#pragma unroll
    for (int ct = 0; ct < 8; ++ct)
#pragma unroll
        for (int rr = 0; rr < 4; ++rr) o[ct][rr] = 0.f;
    float mrun = -1e30f, lpart = 0.f;

    // prologue: stage tile 0 into kv[0]
    int itg0 = sp * 8;
    {
        const u16* ps = &ppf[(size_t)(b * 32 + itg0) * 4096];
        const u16* gs = &gpf[(size_t)(b * 32 + itg0) * 4096];
        *(u16x8*)&kv[0][tid * 8]        = *(const u16x8*)&ps[tid * 8];
        *(u16x8*)&kv[0][2048 + tid * 8] = *(const u16x8*)&ps[2048 + tid * 8];
        *(u16x8*)&kv[0][4096 + tid * 8] = *(const u16x8*)&gs[tid * 8];
        *(u16x8*)&kv[0][6144 + tid * 8] = *(const u16x8*)&gs[2048 + tid * 8];
    }
    __syncthreads();
    int cur = 0;

    for (int it = 0; it < 8; ++it) {
        // (A) issue next tile's global loads early (latency hides under compute)
        u16x8 r0, r1, r2, r3;
        if (it < 7) {
            const u16* ps = &ppf[(size_t)(b * 32 + itg0 + it + 1) * 4096];
            const u16* gs = &gpf[(size_t)(b * 32 + itg0 + it + 1) * 4096];
            r0 = *(const u16x8*)&ps[tid * 8];
            r1 = *(const u16x8*)&ps[2048 + tid * 8];
            r2 = *(const u16x8*)&gs[tid * 8];
            r3 = *(const u16x8*)&gs[2048 + tid * 8];
        }
        // (B) QK^T from kv[cur]
        f32x4 s0 = {0.f, 0.f, 0.f, 0.f}, s1 = {0.f, 0.f, 0.f, 0.f};
        __builtin_amdgcn_s_setprio(1);
#pragma unroll
        for (int ks = 0; ks < 4; ++ks) {
            f16x8 pa0 = ldh8(&kv[cur][ks * 512 + lane * 8]);
            f16x8 pa1 = ldh8(&kv[cur][(4 + ks) * 512 + lane * 8]);
            s0 = MFMAH(pa0, qf[ks], s0);
            s1 = MFMAH(pa1, qf[ks], s1);
        }
        __builtin_amdgcn_s_setprio(0);
        // lane-local max; ballot-gated lazy rescale (P bounded by e^8, fp16-safe)
        float pm8 = s0[0];
#pragma unroll
        for (int rr = 1; rr < 4; ++rr) pm8 = fmaxf(pm8, s0[rr]);
#pragma unroll
        for (int rr = 0; rr < 4; ++rr) pm8 = fmaxf(pm8, s1[rr]);
        if (__any(pm8 > mrun + 8.0f)) {
            float pm = fmaxf(pm8, __shfl_xor(pm8, 16));
            pm = fmaxf(pm, __shfl_xor(pm, 32));
            float mnew = fmaxf(mrun, pm);
            float sc = __expf(mrun - mnew);
#pragma unroll
            for (int ct = 0; ct < 8; ++ct)
#pragma unroll
                for (int rr = 0; rr < 4; ++rr) o[ct][rr] *= sc;
            lpart *= sc;
            mrun = mnew;
        }
        float p[8];
#pragma unroll
        for (int rr = 0; rr < 4; ++rr) { p[rr] = __expf(s0[rr] - mrun); lpart += p[rr]; }
#pragma unroll
        for (int rr = 0; rr < 4; ++rr) { p[4 + rr] = __expf(s1[rr] - mrun); lpart += p[4 + rr]; }
        u16x4 pk0, pk1;
#pragma unroll
        for (int rr = 0; rr < 4; ++rr) { pk0[rr] = f2h(p[rr]); pk1[rr] = f2h(p[4 + rr]); }
        *reinterpret_cast<u16x4*>(&plds[w][l15][g16 * 4]) = pk0;
        *reinterpret_cast<u16x4*>(&plds[w][l15][16 + g16 * 4]) = pk1;
        __syncthreads();  // plds visible
        // (C) PV from plds + kv[cur]
        f16x8 pfr = ldh8(&plds[w][l15][g16 * 8]);
        __builtin_amdgcn_s_setprio(1);
#pragma unroll
        for (int ct = 0; ct < 8; ++ct) {
            f16x8 gfr = ldh8(&kv[cur][4096 + ct * 512 + lane * 8]);
            o[ct] = MFMAH(gfr, pfr, o[ct]);
        }
        __builtin_amdgcn_s_setprio(0);
        // (D) write next tile into the other buffer (vmcnt waits here, overlapped)
        if (it < 7) {
            *(u16x8*)&kv[cur ^ 1][tid * 8]        = r0;
            *(u16x8*)&kv[cur ^ 1][2048 + tid * 8] = r1;
            *(u16x8*)&kv[cur ^ 1][4096 + tid * 8] = r2;
            *(u16x8*)&kv[cur ^ 1][6144 + tid * 8] = r3;
        }
        __syncthreads();  // kv[cur^1] staged + plds reads done
        cur ^= 1;
    }
    // column l-sum: single reduce after the loop
    float lcol = lpart + __shfl_xor(lpart, 16);
    lcol += __shfl_xor(lcol, 32);
    float linv = 1.f / lcol;
    size_t obase = ((size_t)(b * 4 + sp) * N_ + n) * CI_;
#pragma unroll
    for (int ct = 0; ct < 8; ++ct) {
        u16x4 pk;
#pragma unroll
        for (int rr = 0; rr < 4; ++rr) pk[rr] = f2h(o[ct][rr] * linv);
        *reinterpret_cast<u16x4*>(&of[obase + ct * 16 + g16 * 4]) = pk;
    }
    if (g16 == 0) ml[(size_t)(b * 4 + sp) * N_ + n] = make_float2(mrun, lcol);
}

// ---------------- W conv GEMM (fused 4-split combine + fp16 GEMM) ----------------
__global__ __launch_bounds__(256) void k_wconv(
    const u16* __restrict__ wwf, const float* __restrict__ Wb,
    const u16* __restrict__ of, const float2* __restrict__ ml,
    u16* __restrict__ z) {
    int bid = blockIdx.x;
    int b = bid >> 6, rem = bid & 63, ct2 = rem >> 5, nt = rem & 31;
    int w = threadIdx.x >> 6, lane = threadIdx.x & 63;
    int l15 = lane & 15, g16 = lane >> 4;
    int nbase = nt * 128 + (w >> 1) * 64;
    int cbase = ct2 * 128 + (w & 1) * 64;
    const size_t spstride = (size_t)N_ * CI_;
    float wsp[4][4];
#pragma unroll
    for (int i = 0; i < 4; ++i) {
        int n = nbase + i * 16 + l15;
        float2 m0 = ml[(size_t)(b * 4 + 0) * N_ + n];
        float2 m1 = ml[(size_t)(b * 4 + 1) * N_ + n];
        float2 m2 = ml[(size_t)(b * 4 + 2) * N_ + n];
        float2 m3 = ml[(size_t)(b * 4 + 3) * N_ + n];
        float M = fmaxf(fmaxf(m0.x, m1.x), fmaxf(m2.x, m3.x));
        float w0 = __expf(m0.x - M) * m0.y;
        float w1 = __expf(m1.x - M) * m1.y;
        float w2 = __expf(m2.x - M) * m2.y;
        float w3 = __expf(m3.x - M) * m3.y;
        float invL = 1.f / (w0 + w1 + w2 + w3);
        wsp[i][0] = w0 * invL;
        wsp[i][1] = w1 * invL;
        wsp[i][2] = w2 * invL;
        wsp[i][3] = w3 * invL;
    }
    f32x4 acc[4][4];
#pragma unroll
    for (int i = 0; i < 4; ++i)
#pragma unroll
        for (int j = 0; j < 4; ++j)
#pragma unroll
            for (int r = 0; r < 4; ++r) acc[i][j][r] = 0.f;
#pragma unroll
    for (int ks = 0; ks < 4; ++ks) {
        f16x8 a[4], bb[4];
#pragma unroll
        for (int i = 0; i < 4; ++i) {
            int n = nbase + i * 16 + l15;
            size_t base = ((size_t)(b * 4) * N_ + n) * CI_ + ks * 32 + g16 * 8;
            u16x8 v0 = *(const u16x8*)&of[base];
            u16x8 v1 = *(const u16x8*)&of[base + spstride];
            u16x8 v2 = *(const u16x8*)&of[base + 2 * spstride];
            u16x8 v3 = *(const u16x8*)&of[base + 3 * spstride];
            f16x8 av;
#pragma unroll
            for (int e = 0; e < 8; ++e) {
                float vv = h2f(v0[e]) * wsp[i][0] + h2f(v1[e]) * wsp[i][1] +
                           h2f(v2[e]) * wsp[i][2] + h2f(v3[e]) * wsp[i][3];
                av[e] = (_Float16)vv;
            }
            a[i] = av;
        }
#pragma unroll
        for (int j = 0; j < 4; ++j)
            bb[j] = ldh8(&wwf[((size_t)((cbase >> 4) + j) * 4 + ks) * 512 + (size_t)lane * 8]);
#pragma unroll
        for (int i = 0; i < 4; ++i)
#pragma unroll
            for (int j = 0; j < 4; ++j) acc[i][j] = MFMAH(a[i], bb[j], acc[i][j]);
    }
#pragma unroll
    for (int j = 0; j < 4; ++j) {
        int ch = cbase + j * 16 + l15;
        float bias = Wb[ch];
        size_t rowbase = ((size_t)b * C_ + ch) * N_;
#pragma unroll
        for (int i = 0; i < 4; ++i) {
            u16x4 pk;
#pragma unroll
            for (int r = 0; r < 4; ++r) pk[r] = f2h(acc[i][j][r] + bias);
            *reinterpret_cast<u16x4*>(&z[rowbase + nbase + i * 16 + g16 * 4]) = pk;
        }
    }
}

// ---------------- BN stats + finalize ----------------
__global__ __launch_bounds__(256) void k_stats(
    const u16* __restrict__ z, const float* __restrict__ gamma,
    const float* __restrict__ beta, float* __restrict__ bnp) {
    int c = blockIdx.x;
    int tid = threadIdx.x;
    float s = 0.f, q = 0.f;
#pragma unroll
    for (int b = 0; b < B_; ++b) {
        size_t base = ((size_t)b * C_ + c) * N_ + tid * 16;
        u16x8 v0 = *(const u16x8*)&z[base];
        u16x8 v1 = *(const u16x8*)&z[base + 8];
#pragma unroll
        for (int e = 0; e < 8; ++e) {
            float v = h2f(v0[e]);
            s += v;
            q += v * v;
            float u = h2f(v1[e]);
            s += u;
            q += u * u;
        }
    }
#pragma unroll
    for (int off = 1; off <= 32; off <<= 1) {
        s += __shfl_xor(s, off);
        q += __shfl_xor(q, off);
    }
    __shared__ float ss[4], qq[4];
    int w = tid >> 6;
    if ((tid & 63) == 0) {
        ss[w] = s;
        qq[w] = q;
    }
    __syncthreads();
    if (tid == 0) {
        s = ss[0] + ss[1] + ss[2] + ss[3];
        q = qq[0] + qq[1] + qq[2] + qq[3];
        const float inv_n = 1.f / 32768.f;
        float mean = s * inv_n;
        float var = q * inv_n - mean * mean;
        float sc = gamma[c] * rsqrtf(var + 1e-5f);
        bnp[c] = sc;
        bnp[256 + c] = beta[c] - mean * sc;
    }
}

// ---------------- apply BN + residual ----------------
__global__ __launch_bounds__(256) void k_final(
    const float* __restrict__ x, const u16* __restrict__ z,
    const float* __restrict__ bnp, float* __restrict__ out) {
    int i4 = blockIdx.x * 256 + threadIdx.x;
    size_t flat = (size_t)i4 * 4;
    int c = (int)((flat >> 12) & 255);
    float sc = bnp[c], sh = bnp[256 + c];
    float4 xx = *(const float4*)&x[flat];
    u16x4 zz = *(const u16x4*)&z[flat];
    float4 oo;
    oo.x = xx.x + h2f(zz[0]) * sc + sh;
    oo.y = xx.y + h2f(zz[1]) * sc + sh;
    oo.z = xx.z + h2f(zz[2]) * sc + sh;
    oo.w = xx.w + h2f(zz[3]) * sc + sh;
    *(float4*)&out[flat] = oo;
}

extern "C" void kernel_launch(void* const* d_in, const int* in_sizes, int n_in,
                              void* d_out, int out_size, void* d_ws, size_t ws_size,
                              hipStream_t stream) {
    const float* x     = (const float*)d_in[0];
    const float* tw    = (const float*)d_in[1];
    const float* tb    = (const float*)d_in[2];
    const float* pw    = (const float*)d_in[3];
    const float* pb    = (const float*)d_in[4];
    const float* gw    = (const float*)d_in[5];
    const float* gb    = (const float*)d_in[6];
    const float* Ww    = (const float*)d_in[7];
    const float* Wb    = (const float*)d_in[8];
    const float* gamma = (const float*)d_in[9];
    const float* beta  = (const float*)d_in[10];
    float* out = (float*)d_out;

    char* p = (char*)d_ws;
    auto alloc = [&](size_t bytes) {
        char* r = p;
        p += (bytes + 255) & ~(size_t)255;
        return r;
    };
    u16* xbf_h = (u16*)alloc((size_t)B_ * N_ * C_ * 2);      // dead after k_proj
    u16* xbf_l = (u16*)alloc((size_t)B_ * N_ * C_ * 2);      // contiguous after xbf_h
    u16* thf   = (u16*)alloc((size_t)B_ * N_ * CI_ * 2);     // dead after k_attn
    u16* ppf   = (u16*)alloc((size_t)B_ * M_ * CI_ * 2);
    u16* gpf   = (u16*)alloc((size_t)B_ * M_ * CI_ * 2);
    float2* ml = (float2*)alloc((size_t)4 * B_ * N_ * 8);
    u16* z     = (u16*)alloc((size_t)B_ * C_ * N_ * 2);      // live with of
    u16* wcf_h = (u16*)alloc(384 * 256 * 2);
    u16* wcf_l = (u16*)alloc(384 * 256 * 2);
    u16* wwf   = (u16*)alloc(256 * 128 * 2);
    float* bcat = (float*)alloc(384 * 4);
    float* bnp  = (float*)alloc(512 * 4);
    // of (4 x 8.4 MiB fp16 partials = 33.5 MiB) aliases xbf_h+xbf_l (contiguous,
    // dead before k_attn writes).
    u16* of = xbf_h;

    k_prep<<<514, 256, 0, stream>>>(tw, tb, pw, pb, gw, gb, Ww, wcf_h, wcf_l, bcat, wwf);
    k_tx<<<2048, 256, 0, stream>>>(x, xbf_h, xbf_l);
    k_proj<<<768, 256, 0, stream>>>(wcf_h, wcf_l, bcat, xbf_h, xbf_l, thf, ppf, gpf);
    k_attn<<<2048, 256, 0, stream>>>(thf, ppf, gpf, of, ml);
    k_wconv<<<512, 256, 0, stream>>>(wwf, Wb, of, ml, z);
    k_stats<<<256, 256, 0, stream>>>(z, gamma, beta, bnp);
    k_final<<<8192, 256, 0, stream>>>(x, z, bnp, out);
}

// Round 14
// 110.717 us; speedup vs baseline: 1.1659x; 1.1471x over previous
//
#include <hip/hip_runtime.h>

#define B_ 8
#define C_ 256
#define CI_ 128
#define N_ 4096
#define M_ 1024

typedef unsigned short u16;
typedef unsigned int u32;
typedef _Float16 f16x8 __attribute__((ext_vector_type(8)));
typedef float f32x4 __attribute__((ext_vector_type(4)));
typedef u16 u16x4 __attribute__((ext_vector_type(4)));
typedef u16 u16x8 __attribute__((ext_vector_type(8)));

__device__ __forceinline__ u16 f2h(float f) {
    _Float16 h = (_Float16)f;
    u16 u;
    __builtin_memcpy(&u, &h, 2);
    return u;
}
__device__ __forceinline__ float h2f(u16 u) {
    _Float16 h;
    __builtin_memcpy(&h, &u, 2);
    return (float)h;
}
__device__ __forceinline__ f16x8 ldh8(const u16* p) {
    return *reinterpret_cast<const f16x8*>(p);
}
__device__ __forceinline__ f32x4 MFMAH(f16x8 a, f16x8 b, f32x4 c) {
    return __builtin_amdgcn_mfma_f32_16x16x32_f16(a, b, c, 0, 0, 0);
}

// fragment-linear layout: [tile16][ks][lane(64)][8]; value (row-in-16 = lane&15,
// k = ks*32 + (lane>>4)*8 + e). Same layout serves as A-frag (row) or B-frag (col).

// ---------------- weight prep (fp16) ----------------
__global__ __launch_bounds__(256) void k_prep(
    const float* __restrict__ tw, const float* __restrict__ tb,
    const float* __restrict__ pw, const float* __restrict__ pb,
    const float* __restrict__ gw, const float* __restrict__ gb,
    const float* __restrict__ Ww,
    u16* __restrict__ wcf, float* __restrict__ bcat, u16* __restrict__ wwf) {
    int idx = blockIdx.x * 256 + threadIdx.x;
    if (idx < 384 * 256) {
        int r = idx >> 8, c = idx & 255;
        float v = (r < 128) ? tw[r * 256 + c]
                : (r < 256) ? pw[(r - 128) * 256 + c]
                            : gw[(r - 256) * 256 + c];
        size_t off = (size_t)((r >> 4) * 8 + (c >> 5)) * 512 +
                     (((c >> 3) & 3) * 16 + (r & 15)) * 8 + (c & 7);
        wcf[off] = f2h(v);
    } else if (idx < 384 * 256 + 256 * 128) {
        int k2 = idx - 384 * 256;
        int c = k2 >> 7, k = k2 & 127;
        size_t off = (size_t)((c >> 4) * 4 + (k >> 5)) * 512 +
                     (((k >> 3) & 3) * 16 + (c & 15)) * 8 + (k & 7);
        wwf[off] = f2h(Ww[k2]);
    } else if (idx < 384 * 256 + 256 * 128 + 384) {
        int r = idx - (384 * 256 + 256 * 128);
        bcat[r] = (r < 128) ? tb[r] : (r < 256) ? pb[r - 128] : gb[r - 256];
    }
}

// ---------------- x (B,C,N) fp32 -> fragment-linear fp16 ----------------
__global__ __launch_bounds__(256) void k_tx(const float* __restrict__ x,
                                            u16* __restrict__ xbf) {
    int bid = blockIdx.x;
    int b = bid >> 8, rem = bid & 255, nt = rem >> 2, ct = rem & 3;
    int n0 = nt * 64, c0 = ct * 64;
    __shared__ u16 th_[64][66];
    int j = threadIdx.x & 63, i0 = threadIdx.x >> 6;
    for (int i = i0; i < 64; i += 4)
        th_[i][j] = f2h(x[((size_t)b * C_ + c0 + i) * N_ + n0 + j]);
    __syncthreads();
    int w = threadIdx.x >> 6, lane = threadIdx.x & 63;
    int l15 = lane & 15, g16 = lane >> 4;
    int s = w;
#pragma unroll
    for (int kk = 0; kk < 2; ++kk) {
        u16x8 hv;
#pragma unroll
        for (int e = 0; e < 8; ++e)
            hv[e] = th_[kk * 32 + g16 * 8 + e][s * 16 + l15];
        size_t off = ((size_t)(b * 256 + (n0 >> 4) + s) * 8 + (c0 >> 5) + kk) * 512 +
                     (size_t)lane * 8;
        *(u16x8*)&xbf[off] = hv;
    }
}

// ---------------- projection GEMM (fp16) + fused 2x2 pooling epilogue ----------------
__global__ __launch_bounds__(256) void k_proj(
    const u16* __restrict__ wcf, const float* __restrict__ bcat,
    const u16* __restrict__ xbf,
    u16* __restrict__ thf, u16* __restrict__ ppf, u16* __restrict__ gpf) {
    int bid = blockIdx.x;
    int b = bid / 96, rem = bid % 96, rt = rem >> 5, nt = rem & 31;
    int tid = threadIdx.x;
    int w = tid >> 6, lane = tid & 63;
    int l15 = lane & 15, g16 = lane >> 4;
    int wr = (w >> 1) * 64, wc = (w & 1) * 64;
    int rbase = rt * 128 + wr, nbase = nt * 128 + wc;
    __shared__ u16 tl[128][132];
    f32x4 acc[4][4];
#pragma unroll
    for (int i = 0; i < 4; ++i)
#pragma unroll
        for (int j = 0; j < 4; ++j)
#pragma unroll
            for (int r = 0; r < 4; ++r) acc[i][j][r] = 0.f;
#pragma unroll
    for (int ks = 0; ks < 8; ++ks) {
        f16x8 a[4], bb[4];
#pragma unroll
        for (int i = 0; i < 4; ++i)
            a[i] = ldh8(&wcf[((size_t)((rbase >> 4) + i) * 8 + ks) * 512 + (size_t)lane * 8]);
#pragma unroll
        for (int j = 0; j < 4; ++j)
            bb[j] = ldh8(&xbf[((size_t)(b * 256 + (nbase >> 4) + j) * 8 + ks) * 512 +
                              (size_t)lane * 8]);
#pragma unroll
        for (int i = 0; i < 4; ++i)
#pragma unroll
            for (int j = 0; j < 4; ++j) acc[i][j] = MFMAH(a[i], bb[j], acc[i][j]);
    }
    if (rt == 0) {
#pragma unroll
        for (int i = 0; i < 4; ++i) {
            int lrow = wr + i * 16 + g16 * 4;
#pragma unroll
            for (int j = 0; j < 4; ++j) {
                u16x4 pk;
#pragma unroll
                for (int r = 0; r < 4; ++r)
                    pk[r] = f2h(acc[i][j][r] + bcat[lrow + r]);
                size_t off = ((size_t)(b * 256 + (nbase >> 4) + j) * 4 + (lrow >> 5)) * 512 +
                             (((lrow >> 3) & 3) * 16 + l15) * 8 + (lrow & 7);
                *reinterpret_cast<u16x4*>(&thf[off]) = pk;
            }
        }
    } else {
#pragma unroll
        for (int i = 0; i < 4; ++i) {
            int lrow = wr + i * 16 + g16 * 4;
#pragma unroll
            for (int j = 0; j < 4; ++j) {
                int n_loc = wc + j * 16 + l15;
                u16x4 pk;
#pragma unroll
                for (int r = 0; r < 4; ++r)
                    pk[r] = f2h(acc[i][j][r] + bcat[rt * 128 + lrow + r]);
                *reinterpret_cast<u16x4*>(&tl[n_loc][lrow]) = pk;
            }
        }
        __syncthreads();
        if (rt == 1) {
#pragma unroll
            for (int half = 0; half < 2; ++half) {
                int w2 = (tid >> 4) + half * 16;
                int c8 = tid & 15;
                u16x8 v0 = *(const u16x8*)&tl[2 * w2][c8 * 8];
                u16x8 v1 = *(const u16x8*)&tl[2 * w2 + 1][c8 * 8];
                u16x8 v2 = *(const u16x8*)&tl[64 + 2 * w2][c8 * 8];
                u16x8 v3 = *(const u16x8*)&tl[65 + 2 * w2][c8 * 8];
                u16x8 o;
#pragma unroll
                for (int e = 0; e < 8; ++e) {
                    float mx = fmaxf(fmaxf(h2f(v0[e]), h2f(v1[e])),
                                     fmaxf(h2f(v2[e]), h2f(v3[e])));
                    o[e] = f2h(mx);
                }
                size_t off = ((size_t)(((b * 32 + nt) * 2 + (w2 >> 4)) * 4 + (c8 >> 2)) * 64 +
                              (c8 & 3) * 16 + (w2 & 15)) * 8;
                *(u16x8*)&ppf[off] = o;
            }
        } else {
#pragma unroll
            for (int s = 0; s < 2; ++s) {
                int wg = (tid >> 7) + s * 2;
                int ci = tid & 127;
                u16x8 o;
#pragma unroll
                for (int e = 0; e < 8; ++e) {
                    int w2 = wg * 8 + e;
                    float v = fmaxf(fmaxf(h2f(tl[2 * w2][ci]), h2f(tl[2 * w2 + 1][ci])),
                                    fmaxf(h2f(tl[64 + 2 * w2][ci]), h2f(tl[65 + 2 * w2][ci])));
                    o[e] = f2h(v);
                }
                size_t off = ((size_t)((b * 32 + nt) * 8 + (ci >> 4)) * 64 + wg * 16 +
                              (ci & 15)) * 8;
                *(u16x8*)&gpf[off] = o;
            }
        }
    }
}

// ---------------- flash attention (split-m=4, double-buffered KV in LDS) -------
__global__ __launch_bounds__(256) void k_attn(
    const u16* __restrict__ thf, const u16* __restrict__ ppf,
    const u16* __restrict__ gpf,
    u16* __restrict__ of, float2* __restrict__ ml) {
    int bid = blockIdx.x;
    int b = bid & 7, r = bid >> 3;   // same-b blocks -> same XCD (L2 locality)
    int sp = r >> 6, nt = r & 63;    // sp in 0..3
    int tid = threadIdx.x;
    int w = tid >> 6, lane = tid & 63;
    int l15 = lane & 15, g16 = lane >> 4;
    int n = nt * 64 + w * 16 + l15;
    int t16 = nt * 4 + w;
    __shared__ u16 kv[2][8192];       // [buf][0..4096): K-tile, [4096..8192): V-tile
    __shared__ u16 plds[4][16][40];   // per-warp P transpose, padded

    f16x8 qf[4];
#pragma unroll
    for (int ks = 0; ks < 4; ++ks)
        qf[ks] = ldh8(&thf[((size_t)(b * 256 + t16) * 4 + ks) * 512 + (size_t)lane * 8]);

    f32x4 o[8];
#pragma unroll
    for (int ct = 0; ct < 8; ++ct)
#pragma unroll
        for (int rr = 0; rr < 4; ++rr) o[ct][rr] = 0.f;
    float mrun = -1e30f, lpart = 0.f;

    // prologue: stage tile 0 into kv[0]
    int itg0 = sp * 8;
    {
        const u16* ps = &ppf[(size_t)(b * 32 + itg0) * 4096];
        const u16* gs = &gpf[(size_t)(b * 32 + itg0) * 4096];
        *(u16x8*)&kv[0][tid * 8]        = *(const u16x8*)&ps[tid * 8];
        *(u16x8*)&kv[0][2048 + tid * 8] = *(const u16x8*)&ps[2048 + tid * 8];
        *(u16x8*)&kv[0][4096 + tid * 8] = *(const u16x8*)&gs[tid * 8];
        *(u16x8*)&kv[0][6144 + tid * 8] = *(const u16x8*)&gs[2048 + tid * 8];
    }
    __syncthreads();
    int cur = 0;

    for (int it = 0; it < 8; ++it) {
        // (A) issue next tile's global loads early (latency hides under compute)
        u16x8 r0, r1, r2, r3;
        if (it < 7) {
            const u16* ps = &ppf[(size_t)(b * 32 + itg0 + it + 1) * 4096];
            const u16* gs = &gpf[(size_t)(b * 32 + itg0 + it + 1) * 4096];
            r0 = *(const u16x8*)&ps[tid * 8];
            r1 = *(const u16x8*)&ps[2048 + tid * 8];
            r2 = *(const u16x8*)&gs[tid * 8];
            r3 = *(const u16x8*)&gs[2048 + tid * 8];
        }
        // (B) QK^T from kv[cur]
        f32x4 s0 = {0.f, 0.f, 0.f, 0.f}, s1 = {0.f, 0.f, 0.f, 0.f};
        __builtin_amdgcn_s_setprio(1);
#pragma unroll
        for (int ks = 0; ks < 4; ++ks) {
            f16x8 pa0 = ldh8(&kv[cur][ks * 512 + lane * 8]);
            f16x8 pa1 = ldh8(&kv[cur][(4 + ks) * 512 + lane * 8]);
            s0 = MFMAH(pa0, qf[ks], s0);
            s1 = MFMAH(pa1, qf[ks], s1);
        }
        __builtin_amdgcn_s_setprio(0);
        // lane-local max; ballot-gated lazy rescale (P bounded by e^8, fp16-safe)
        float pm8 = s0[0];
#pragma unroll
        for (int rr = 1; rr < 4; ++rr) pm8 = fmaxf(pm8, s0[rr]);
#pragma unroll
        for (int rr = 0; rr < 4; ++rr) pm8 = fmaxf(pm8, s1[rr]);
        if (__any(pm8 > mrun + 8.0f)) {
            float pm = fmaxf(pm8, __shfl_xor(pm8, 16));
            pm = fmaxf(pm, __shfl_xor(pm, 32));
            float mnew = fmaxf(mrun, pm);
            float sc = __expf(mrun - mnew);
#pragma unroll
            for (int ct = 0; ct < 8; ++ct)
#pragma unroll
                for (int rr = 0; rr < 4; ++rr) o[ct][rr] *= sc;
            lpart *= sc;
            mrun = mnew;
        }
        float p[8];
#pragma unroll
        for (int rr = 0; rr < 4; ++rr) { p[rr] = __expf(s0[rr] - mrun); lpart += p[rr]; }
#pragma unroll
        for (int rr = 0; rr < 4; ++rr) { p[4 + rr] = __expf(s1[rr] - mrun); lpart += p[4 + rr]; }
        u16x4 pk0, pk1;
#pragma unroll
        for (int rr = 0; rr < 4; ++rr) { pk0[rr] = f2h(p[rr]); pk1[rr] = f2h(p[4 + rr]); }
        *reinterpret_cast<u16x4*>(&plds[w][l15][g16 * 4]) = pk0;
        *reinterpret_cast<u16x4*>(&plds[w][l15][16 + g16 * 4]) = pk1;
        __syncthreads();  // plds visible
        // (C) PV from plds + kv[cur]
        f16x8 pfr = ldh8(&plds[w][l15][g16 * 8]);
        __builtin_amdgcn_s_setprio(1);
#pragma unroll
        for (int ct = 0; ct < 8; ++ct) {
            f16x8 gfr = ldh8(&kv[cur][4096 + ct * 512 + lane * 8]);
            o[ct] = MFMAH(gfr, pfr, o[ct]);
        }
        __builtin_amdgcn_s_setprio(0);
        // (D) write next tile into the other buffer (vmcnt waits here, overlapped)
        if (it < 7) {
            *(u16x8*)&kv[cur ^ 1][tid * 8]        = r0;
            *(u16x8*)&kv[cur ^ 1][2048 + tid * 8] = r1;
            *(u16x8*)&kv[cur ^ 1][4096 + tid * 8] = r2;
            *(u16x8*)&kv[cur ^ 1][6144 + tid * 8] = r3;
        }
        __syncthreads();  // kv[cur^1] staged + plds reads done
        cur ^= 1;
    }
    // column l-sum: single reduce after the loop
    float lcol = lpart + __shfl_xor(lpart, 16);
    lcol += __shfl_xor(lcol, 32);
    float linv = 1.f / lcol;
    size_t obase = ((size_t)(b * 4 + sp) * N_ + n) * CI_;
#pragma unroll
    for (int ct = 0; ct < 8; ++ct) {
        u16x4 pk;
#pragma unroll
        for (int rr = 0; rr < 4; ++rr) pk[rr] = f2h(o[ct][rr] * linv);
        *reinterpret_cast<u16x4*>(&of[obase + ct * 16 + g16 * 4]) = pk;
    }
    if (g16 == 0) ml[(size_t)(b * 4 + sp) * N_ + n] = make_float2(mrun, lcol);
}

// ---------------- W conv GEMM (fused 4-split combine + fp16 GEMM) ----------------
__global__ __launch_bounds__(256) void k_wconv(
    const u16* __restrict__ wwf, const float* __restrict__ Wb,
    const u16* __restrict__ of, const float2* __restrict__ ml,
    u16* __restrict__ z) {
    int bid = blockIdx.x;
    int b = bid >> 6, rem = bid & 63, ct2 = rem >> 5, nt = rem & 31;
    int w = threadIdx.x >> 6, lane = threadIdx.x & 63;
    int l15 = lane & 15, g16 = lane >> 4;
    int nbase = nt * 128 + (w >> 1) * 64;
    int cbase = ct2 * 128 + (w & 1) * 64;
    const size_t spstride = (size_t)N_ * CI_;
    float wsp[4][4];
#pragma unroll
    for (int i = 0; i < 4; ++i) {
        int n = nbase + i * 16 + l15;
        float2 m0 = ml[(size_t)(b * 4 + 0) * N_ + n];
        float2 m1 = ml[(size_t)(b * 4 + 1) * N_ + n];
        float2 m2 = ml[(size_t)(b * 4 + 2) * N_ + n];
        float2 m3 = ml[(size_t)(b * 4 + 3) * N_ + n];
        float M = fmaxf(fmaxf(m0.x, m1.x), fmaxf(m2.x, m3.x));
        float w0 = __expf(m0.x - M) * m0.y;
        float w1 = __expf(m1.x - M) * m1.y;
        float w2 = __expf(m2.x - M) * m2.y;
        float w3 = __expf(m3.x - M) * m3.y;
        float invL = 1.f / (w0 + w1 + w2 + w3);
        wsp[i][0] = w0 * invL;
        wsp[i][1] = w1 * invL;
        wsp[i][2] = w2 * invL;
        wsp[i][3] = w3 * invL;
    }
    f32x4 acc[4][4];
#pragma unroll
    for (int i = 0; i < 4; ++i)
#pragma unroll
        for (int j = 0; j < 4; ++j)
#pragma unroll
            for (int r = 0; r < 4; ++r) acc[i][j][r] = 0.f;
#pragma unroll
    for (int ks = 0; ks < 4; ++ks) {
        f16x8 a[4], bb[4];
#pragma unroll
        for (int i = 0; i < 4; ++i) {
            int n = nbase + i * 16 + l15;
            size_t base = ((size_t)(b * 4) * N_ + n) * CI_ + ks * 32 + g16 * 8;
            u16x8 v0 = *(const u16x8*)&of[base];
            u16x8 v1 = *(const u16x8*)&of[base + spstride];
            u16x8 v2 = *(const u16x8*)&of[base + 2 * spstride];
            u16x8 v3 = *(const u16x8*)&of[base + 3 * spstride];
            f16x8 av;
#pragma unroll
            for (int e = 0; e < 8; ++e) {
                float vv = h2f(v0[e]) * wsp[i][0] + h2f(v1[e]) * wsp[i][1] +
                           h2f(v2[e]) * wsp[i][2] + h2f(v3[e]) * wsp[i][3];
                av[e] = (_Float16)vv;
            }
            a[i] = av;
        }
#pragma unroll
        for (int j = 0; j < 4; ++j)
            bb[j] = ldh8(&wwf[((size_t)((cbase >> 4) + j) * 4 + ks) * 512 + (size_t)lane * 8]);
#pragma unroll
        for (int i = 0; i < 4; ++i)
#pragma unroll
            for (int j = 0; j < 4; ++j) acc[i][j] = MFMAH(a[i], bb[j], acc[i][j]);
    }
#pragma unroll
    for (int j = 0; j < 4; ++j) {
        int ch = cbase + j * 16 + l15;
        float bias = Wb[ch];
        size_t rowbase = ((size_t)b * C_ + ch) * N_;
#pragma unroll
        for (int i = 0; i < 4; ++i) {
            u16x4 pk;
#pragma unroll
            for (int r = 0; r < 4; ++r) pk[r] = f2h(acc[i][j][r] + bias);
            *reinterpret_cast<u16x4*>(&z[rowbase + nbase + i * 16 + g16 * 4]) = pk;
        }
    }
}

// ---------------- BN stats + finalize ----------------
__global__ __launch_bounds__(256) void k_stats(
    const u16* __restrict__ z, const float* __restrict__ gamma,
    const float* __restrict__ beta, float* __restrict__ bnp) {
    int c = blockIdx.x;
    int tid = threadIdx.x;
    float s = 0.f, q = 0.f;
#pragma unroll
    for (int b = 0; b < B_; ++b) {
        size_t base = ((size_t)b * C_ + c) * N_ + tid * 16;
        u16x8 v0 = *(const u16x8*)&z[base];
        u16x8 v1 = *(const u16x8*)&z[base + 8];
#pragma unroll
        for (int e = 0; e < 8; ++e) {
            float v = h2f(v0[e]);
            s += v;
            q += v * v;
            float u = h2f(v1[e]);
            s += u;
            q += u * u;
        }
    }
#pragma unroll
    for (int off = 1; off <= 32; off <<= 1) {
        s += __shfl_xor(s, off);
        q += __shfl_xor(q, off);
    }
    __shared__ float ss[4], qq[4];
    int w = tid >> 6;
    if ((tid & 63) == 0) {
        ss[w] = s;
        qq[w] = q;
    }
    __syncthreads();
    if (tid == 0) {
        s = ss[0] + ss[1] + ss[2] + ss[3];
        q = qq[0] + qq[1] + qq[2] + qq[3];
        const float inv_n = 1.f / 32768.f;
        float mean = s * inv_n;
        float var = q * inv_n - mean * mean;
        float sc = gamma[c] * rsqrtf(var + 1e-5f);
        bnp[c] = sc;
        bnp[256 + c] = beta[c] - mean * sc;
    }
}

// ---------------- apply BN + residual ----------------
__global__ __launch_bounds__(256) void k_final(
    const float* __restrict__ x, const u16* __restrict__ z,
    const float* __restrict__ bnp, float* __restrict__ out) {
    int i4 = blockIdx.x * 256 + threadIdx.x;
    size_t flat = (size_t)i4 * 4;
    int c = (int)((flat >> 12) & 255);
    float sc = bnp[c], sh = bnp[256 + c];
    float4 xx = *(const float4*)&x[flat];
    u16x4 zz = *(const u16x4*)&z[flat];
    float4 oo;
    oo.x = xx.x + h2f(zz[0]) * sc + sh;
    oo.y = xx.y + h2f(zz[1]) * sc + sh;
    oo.z = xx.z + h2f(zz[2]) * sc + sh;
    oo.w = xx.w + h2f(zz[3]) * sc + sh;
    *(float4*)&out[flat] = oo;
}

extern "C" void kernel_launch(void* const* d_in, const int* in_sizes, int n_in,
                              void* d_out, int out_size, void* d_ws, size_t ws_size,
                              hipStream_t stream) {
    const float* x     = (const float*)d_in[0];
    const float* tw    = (const float*)d_in[1];
    const float* tb    = (const float*)d_in[2];
    const float* pw    = (const float*)d_in[3];
    const float* pb    = (const float*)d_in[4];
    const float* gw    = (const float*)d_in[5];
    const float* gb    = (const float*)d_in[6];
    const float* Ww    = (const float*)d_in[7];
    const float* Wb    = (const float*)d_in[8];
    const float* gamma = (const float*)d_in[9];
    const float* beta  = (const float*)d_in[10];
    float* out = (float*)d_out;

    char* p = (char*)d_ws;
    auto alloc = [&](size_t bytes) {
        char* r = p;
        p += (bytes + 255) & ~(size_t)255;
        return r;
    };
    u16* xbf   = (u16*)alloc((size_t)B_ * N_ * C_ * 2);          // 16.8 MB
    u16* thf   = (u16*)alloc((size_t)B_ * N_ * CI_ * 2);         // 8.4 MB
    u16* ppf   = (u16*)alloc((size_t)B_ * M_ * CI_ * 2);         // 2.1 MB
    u16* gpf   = (u16*)alloc((size_t)B_ * M_ * CI_ * 2);         // 2.1 MB
    float2* ml = (float2*)alloc((size_t)4 * B_ * N_ * 8);        // 1 MB
    u16* of    = (u16*)alloc((size_t)4 * B_ * N_ * CI_ * 2);     // 33.5 MB
    u16* z     = (u16*)alloc((size_t)B_ * C_ * N_ * 2);          // 16.8 MB
    u16* wcf   = (u16*)alloc(384 * 256 * 2);
    u16* wwf   = (u16*)alloc(256 * 128 * 2);
    float* bcat = (float*)alloc(384 * 4);
    float* bnp  = (float*)alloc(512 * 4);
    // total ~81 MB < R3's proven ~89 MB footprint

    k_prep<<<514, 256, 0, stream>>>(tw, tb, pw, pb, gw, gb, Ww, wcf, bcat, wwf);
    k_tx<<<2048, 256, 0, stream>>>(x, xbf);
    k_proj<<<768, 256, 0, stream>>>(wcf, bcat, xbf, thf, ppf, gpf);
    k_attn<<<2048, 256, 0, stream>>>(thf, ppf, gpf, of, ml);
    k_wconv<<<512, 256, 0, stream>>>(wwf, Wb, of, ml, z);
    k_stats<<<256, 256, 0, stream>>>(z, gamma, beta, bnp);
    k_final<<<8192, 256, 0, stream>>>(x, z, bnp, out);
}